// Round 10
// baseline (72.230 us; speedup 1.0000x reference)
//
#include <hip/hip_runtime.h>
#include <math.h>

// Sparsemax along last dim, rows of d=2048, fp32.
// One wave per row; Michelot tau iteration (exact, no sort) — see R4/R7 notes.
// Reductions on the VALU DPP pipe (row_shr scan + row_bcast + readlane).
//
// Cache partitioning (R10): X is exactly 256 MiB = L3 capacity; cyclic re-read
// at capacity is the replacement worst case (~27% hits measured in R9). Fix:
// pin 5/8 of X (160 MiB) via TEMPORAL loads (allocates in L3, fits w/ headroom),
// stream the remaining 3/8 via NONTEMPORAL loads (no allocate -> no eviction of
// the pinned set). Stores stay nontemporal. Steady-state HBM traffic/replay:
// 96 MB read + 256 MB write instead of ~440 MB.

constexpr int D      = 2048;
constexpr int LANES  = 64;
constexpr int PER    = D / LANES;   // 32 elements per lane
constexpr int WAVES  = 4;           // waves (rows) per block
constexpr int BLOCK  = WAVES * LANES;

typedef float f32x4 __attribute__((ext_vector_type(4)));

// DPP ctrl encodings (gfx9): ROW_SHR|N = 0x110|N, ROW_BCAST15 = 0x142, ROW_BCAST31 = 0x143
#define DPP_MAX_STEP(x, ctrl)                                                        \
    {                                                                                \
        int _t = __builtin_amdgcn_update_dpp(__float_as_int(x), __float_as_int(x),   \
                                             (ctrl), 0xf, 0xf, false);               \
        (x) = fmaxf((x), __int_as_float(_t));                                        \
    }
#define DPP_ADD_STEP(x, ctrl)                                                        \
    {                                                                                \
        int _t = __builtin_amdgcn_update_dpp(0, __float_as_int(x),                   \
                                             (ctrl), 0xf, 0xf, true);                \
        (x) += __int_as_float(_t);                                                   \
    }

__device__ __forceinline__ float wave_max_dpp(float x)
{
    DPP_MAX_STEP(x, 0x111); DPP_MAX_STEP(x, 0x112);
    DPP_MAX_STEP(x, 0x114); DPP_MAX_STEP(x, 0x118);
    DPP_MAX_STEP(x, 0x142); DPP_MAX_STEP(x, 0x143);
    return __int_as_float(__builtin_amdgcn_readlane(__float_as_int(x), 63));
}

__device__ __forceinline__ float wave_sum_dpp(float x)
{
    DPP_ADD_STEP(x, 0x111); DPP_ADD_STEP(x, 0x112);
    DPP_ADD_STEP(x, 0x114); DPP_ADD_STEP(x, 0x118);
    DPP_ADD_STEP(x, 0x142); DPP_ADD_STEP(x, 0x143);
    return __int_as_float(__builtin_amdgcn_readlane(__float_as_int(x), 63));
}

__global__ __launch_bounds__(BLOCK, 8)   // 8 waves/EU
void sparsemax_kernel(const float* __restrict__ X, float* __restrict__ Y,
                      int nrows, int cut_row)
{
    const int wid  = threadIdx.x >> 6;
    const int lane = threadIdx.x & 63;
    const int row  = blockIdx.x * WAVES + wid;
    if (row >= nrows) return;

    const f32x4* __restrict__ px = reinterpret_cast<const f32x4*>(X) + (size_t)row * (D / 4);
    f32x4*       __restrict__ py = reinterpret_cast<f32x4*>(Y)       + (size_t)row * (D / 4);

    // ---- load row: pinned region -> temporal; streamed region -> nontemporal ----
    float a[PER];
    if (row < cut_row) {
        #pragma unroll
        for (int j = 0; j < PER / 4; ++j) {
            f32x4 v = px[j * LANES + lane];
            a[4*j+0] = v.x; a[4*j+1] = v.y; a[4*j+2] = v.z; a[4*j+3] = v.w;
        }
    } else {
        #pragma unroll
        for (int j = 0; j < PER / 4; ++j) {
            f32x4 v = __builtin_nontemporal_load(&px[j * LANES + lane]);
            a[4*j+0] = v.x; a[4*j+1] = v.y; a[4*j+2] = v.z; a[4*j+3] = v.w;
        }
    }

    // ---- row max ----
    float mxl = a[0];
    #pragma unroll
    for (int i = 1; i < PER; ++i) mxl = fmaxf(mxl, a[i]);
    const float mx = wave_max_dpp(mxl);

    // ---- Michelot, unshifted domain, S0 = {x > mx - 1}  (tau* >= -1) ----
    float tau   = -1.0f;
    int   cprev = -1;

    for (int it = 0; it < D; ++it) {              // cap for guaranteed termination
        const float t = mx + tau;
        float sl = 0.0f, cl = 0.0f;
        #pragma unroll
        for (int i = 0; i < PER; ++i) {
            if (a[i] > t) { sl += a[i]; cl += 1.0f; }
        }
        const float s = wave_sum_dpp(sl);
        const float c = wave_sum_dpp(cl);
        tau = (s - c * mx - 1.0f) * __builtin_amdgcn_rcpf(c);   // c >= 1 always
        int ci = (int)c;
        if (ci == cprev) break;                   // same count + nested -> exact
        cprev = ci;
    }

    // ---- dense store: max(x - T, 0), NONTEMPORAL (don't evict pinned X) ----
    const float T = mx + tau;
    #pragma unroll
    for (int j = 0; j < PER / 4; ++j) {
        f32x4 v;
        v.x = fmaxf(a[4*j+0] - T, 0.0f);
        v.y = fmaxf(a[4*j+1] - T, 0.0f);
        v.z = fmaxf(a[4*j+2] - T, 0.0f);
        v.w = fmaxf(a[4*j+3] - T, 0.0f);
        __builtin_nontemporal_store(v, &py[j * LANES + lane]);
    }
}

extern "C" void kernel_launch(void* const* d_in, const int* in_sizes, int n_in,
                              void* d_out, int out_size, void* d_ws, size_t ws_size,
                              hipStream_t stream)
{
    const float* X = reinterpret_cast<const float*>(d_in[0]);
    float*       Y = reinterpret_cast<float*>(d_out);
    const int nrows = in_sizes[0] / D;                 // 32768
    const int cut   = (int)(((long long)nrows * 5) / 8);  // 20480 rows = 160 MiB pinned
    const int grid  = (nrows + WAVES - 1) / WAVES;     // 8192 blocks
    sparsemax_kernel<<<grid, BLOCK, 0, stream>>>(X, Y, nrows, cut);
}